// Round 12
// baseline (113.349 us; speedup 1.0000x reference)
//
#include <hip/hip_runtime.h>

// ---------------------------------------------------------------------------
// PYG_GCN: y = relu(x@W_in+b_in) -> GCNConv(W_gcn,b_gcn) -> relu -> @W_cls+b_cls
// N=50000, E=600000, D=128, C=40.
// R12 A/B: R11 with the gather reverted to R8/R9's lane-owns-2-cols scheme
// (quarter-wave gather suspected regression). Keeps deg-hist under GEMM1 and
// dinv folded into GEMM2 epilogue (L4 = sort only).
// ---------------------------------------------------------------------------

typedef __bf16 bf16x8 __attribute__((ext_vector_type(8)));
typedef float f32x4 __attribute__((ext_vector_type(4)));

#define NBUCK 512      // bucket = col>>7; used 0..390 for N=50000
#define CH_MAX 4704    // max edges per sort-chunk block
#define PREP_BLKS 152  // 38912 weight elements / 256
#define DH 64          // deg-hist blocks in L2

__device__ __forceinline__ ushort f2b(float f) {  // fp32 -> bf16 RNE
  uint u = __float_as_uint(f);
  return (ushort)((u + 0x7FFFu + ((u >> 16) & 1u)) >> 16);
}
__device__ __forceinline__ float b2f_lo(uint u) { return __uint_as_float(u << 16); }
__device__ __forceinline__ float b2f_hi(uint u) { return __uint_as_float(u & 0xFFFF0000u); }

// ---------------- L1: weight prep || coarse chist || zero deg --------------
__global__ __launch_bounds__(256) void k_prep_chist_zero(const float* __restrict__ Wi,
                                                         const float* __restrict__ Wg,
                                                         const float* __restrict__ Wc,
                                                         ushort* __restrict__ Ti,
                                                         ushort* __restrict__ Tg,
                                                         ushort* __restrict__ Tc,
                                                         const int* __restrict__ col,
                                                         int* __restrict__ H2,
                                                         int* __restrict__ deg,
                                                         int E, int chunk, int sortb,
                                                         int n) {
  __shared__ int hist[NBUCK];
  const int tid = threadIdx.x;
  if (blockIdx.x < PREP_BLKS) {
    int idx = blockIdx.x * 256 + tid;
    if (idx < 16384) {
      int c = idx >> 7, k = idx & 127;
      Ti[c * 128 + k] = f2b(Wi[k * 128 + c]);
    } else if (idx < 32768) {
      int j = idx - 16384;
      int c = j >> 7, k = j & 127;
      Tg[c * 128 + k] = f2b(Wg[k * 128 + c]);
    } else if (idx < 38912) {
      int j = idx - 32768;
      int c = j >> 7, k = j & 127;
      Tc[c * 128 + k] = (c < 40) ? f2b(Wc[k * 40 + c]) : (ushort)0;
    }
    return;
  }
  if (blockIdx.x < PREP_BLKS + sortb) {
    const int blk = blockIdx.x - PREP_BLKS;
    for (int b = tid; b < NBUCK; b += 256) hist[b] = 0;
    __syncthreads();
    const int e0 = blk * chunk;
    const int cnt = min(chunk, E - e0);
    for (int i = tid; i < cnt; i += 256)
      atomicAdd(&hist[((unsigned)col[e0 + i]) >> 7], 1);
    __syncthreads();
    for (int b = tid; b < NBUCK; b += 256)
      H2[b * sortb + blk] = hist[b];
    return;
  }
  // zero deg
  const int zb = blockIdx.x - PREP_BLKS - sortb;
  const int i0 = zb * 1024 + tid * 4;
  if (i0 + 3 < n) *(int4*)&deg[i0] = make_int4(0, 0, 0, 0);
  else {
    if (i0 < n) deg[i0] = 0;
    if (i0 + 1 < n) deg[i0 + 1] = 0;
    if (i0 + 2 < n) deg[i0 + 2] = 0;
  }
}

// ---------------- L2: block0 scan || deg-hist || GEMM1 ---------------------
__global__ __launch_bounds__(512) void k_scan_hist_gemm1(const int* __restrict__ H2,
                                                         int* __restrict__ Hs,
                                                         int* __restrict__ cursor,
                                                         int sortb,
                                                         const int* __restrict__ col,
                                                         int* __restrict__ deg,
                                                         int E,
                                                         const float* __restrict__ x,
                                                         const ushort* __restrict__ Wti,
                                                         const float* __restrict__ b_in,
                                                         ushort* __restrict__ h,
                                                         int nrows, int n) {
  __shared__ __align__(16) char smem[69632];
  const int tid = threadIdx.x;
  if (blockIdx.x == 0) {
    int* sd = (int*)smem;  // 512 ints
    int s = 0;
    const int4* p = (const int4*)&H2[tid * sortb];
    for (int j = 0; j < sortb / 4; ++j) { int4 v = p[j]; s += v.x + v.y + v.z + v.w; }
    sd[tid] = s;
    __syncthreads();
    for (int off = 1; off < 512; off <<= 1) {
      int u = (tid >= off) ? sd[tid - off] : 0;
      __syncthreads();
      sd[tid] += u;
      __syncthreads();
    }
    Hs[tid] = sd[tid] - s;          // exclusive
    if (tid == 511) Hs[NBUCK] = sd[511];
    cursor[tid] = 0;
    return;
  }
  if (blockIdx.x <= DH) {
    const int hb = blockIdx.x - 1;
    for (int i = hb * 512 + tid; i < E; i += DH * 512) {
      int c = col[i];
      if ((unsigned)c < (unsigned)n) atomicAdd(&deg[c], 1);
    }
    return;
  }
  // GEMM1: h = relu(x @ W_in + b_in), 128-row tiles, 8 waves
  ushort (*As)[136] = (ushort(*)[136])smem;                    // 128 rows
  ushort (*Bs)[136] = (ushort(*)[136])(smem + 128 * 136 * 2);  // 128 rows
  const int row0 = (blockIdx.x - 1 - DH) * 128;
#pragma unroll
  for (int q = 0; q < 4; ++q) {
    int f = tid + 512 * q;
    int r = f >> 4, cw = f & 15;
    *(uint4*)&Bs[r][cw * 8] = *(const uint4*)&Wti[r * 128 + cw * 8];
  }
#pragma unroll
  for (int q = 0; q < 8; ++q) {
    int f = tid + 512 * q;
    int r = f >> 5, kc = f & 31;
    float4 v = make_float4(0.f, 0.f, 0.f, 0.f);
    if (row0 + r < nrows) v = *(const float4*)&x[(size_t)(row0 + r) * 128 + kc * 4];
    ushort4 o;
    o.x = f2b(v.x); o.y = f2b(v.y); o.z = f2b(v.z); o.w = f2b(v.w);
    *(ushort4*)&As[r][kc * 4] = o;
  }
  __syncthreads();

  const int wid = tid >> 6, lane = tid & 63;
  const int fr = lane & 15, fg = lane >> 4;
  f32x4 acc[8];
#pragma unroll
  for (int nn = 0; nn < 8; ++nn) acc[nn] = (f32x4){0.f, 0.f, 0.f, 0.f};
#pragma unroll
  for (int ks = 0; ks < 4; ++ks) {
    const int kb = ks * 32 + fg * 8;
    bf16x8 a = *(const bf16x8*)&As[wid * 16 + fr][kb];
#pragma unroll
    for (int nn = 0; nn < 8; ++nn) {
      bf16x8 b = *(const bf16x8*)&Bs[nn * 16 + fr][kb];
      acc[nn] = __builtin_amdgcn_mfma_f32_16x16x32_bf16(a, b, acc[nn], 0, 0, 0);
    }
  }
  const int r0 = row0 + wid * 16 + fg * 4;
#pragma unroll
  for (int nn = 0; nn < 8; ++nn) {
    const int cn = nn * 16 + fr;
    const float bv = b_in[cn];
#pragma unroll
    for (int i = 0; i < 4; ++i) {
      const int rr = r0 + i;
      if (rr < nrows) h[(size_t)rr * 128 + cn] = f2b(fmaxf(acc[nn][i] + bv, 0.f));
    }
  }
}

// ---------------- L3: reorder || GEMM2 (xws = dinv[r]*(h@W_gcn)) -----------
// ebuf record: (c_local<<16) | row  (row < 65536 since N=50000).
__global__ __launch_bounds__(256) void k_reorder_gemm2(const int* __restrict__ row,
                                                       const int* __restrict__ col,
                                                       const int* __restrict__ Hs,
                                                       int* __restrict__ cursor,
                                                       uint* __restrict__ ebuf,
                                                       int E, int chunk, int sortb,
                                                       const ushort* __restrict__ h,
                                                       const ushort* __restrict__ Wtg,
                                                       const int* __restrict__ deg,
                                                       ushort* __restrict__ xws,
                                                       int nrows) {
  __shared__ __align__(16) char smem[52224];
  const int tid = threadIdx.x;
  if (blockIdx.x < sortb) {
    int* hist   = (int*)smem;              // NBUCK
    int* lstart = hist + NBUCK;            // NBUCK
    int* cnt2   = lstart + NBUCK;          // NBUCK
    int* obase  = cnt2 + NBUCK;            // NBUCK
    uint* data  = (uint*)(obase + NBUCK);  // CH_MAX
    int* gpos   = (int*)(data + CH_MAX);   // CH_MAX
    int* sd     = gpos + CH_MAX;           // 256
    for (int b = tid; b < NBUCK; b += 256) { hist[b] = 0; cnt2[b] = 0; }
    __syncthreads();
    const int e0 = blockIdx.x * chunk;
    const int cnt = min(chunk, E - e0);
    for (int i = tid; i < cnt; i += 256)
      atomicAdd(&hist[((unsigned)col[e0 + i]) >> 7], 1);
    __syncthreads();
    const int h0 = hist[2 * tid], h1 = hist[2 * tid + 1];
    const int ps = h0 + h1;
    sd[tid] = ps;
    __syncthreads();
    for (int off = 1; off < 256; off <<= 1) {
      int u = (tid >= off) ? sd[tid - off] : 0;
      __syncthreads();
      sd[tid] += u;
      __syncthreads();
    }
    const int ex = sd[tid] - ps;
    lstart[2 * tid] = ex;
    lstart[2 * tid + 1] = ex + h0;
    obase[2 * tid]     = Hs[2 * tid]     + (h0 ? atomicAdd(&cursor[2 * tid], h0) : 0);
    obase[2 * tid + 1] = Hs[2 * tid + 1] + (h1 ? atomicAdd(&cursor[2 * tid + 1], h1) : 0);
    __syncthreads();
    for (int i = tid; i < cnt; i += 256) {
      const int c = col[e0 + i], r = row[e0 + i];
      const int b = ((unsigned)c) >> 7;
      const int rk = atomicAdd(&cnt2[b], 1);
      const int slot = lstart[b] + rk;
      data[slot] = ((uint)(c & 127) << 16) | (uint)r;
      gpos[slot] = obase[b] + rk;
    }
    __syncthreads();
    for (int i = tid; i < cnt; i += 256)
      ebuf[gpos[i]] = data[i];
    return;
  }
  // GEMM2: 64-row tile, 4 waves; epilogue scales by dinv[r]=rsqrt(deg[r]+1)
  ushort (*As)[136] = (ushort(*)[136])smem;                   // 64 rows
  ushort (*Bs)[136] = (ushort(*)[136])(smem + 64 * 136 * 2);  // 128 rows
  const int row0 = (blockIdx.x - sortb) * 64;
#pragma unroll
  for (int q = 0; q < 8; ++q) {
    int f = tid + 256 * q;
    int r = f >> 4, cw = f & 15;
    *(uint4*)&Bs[r][cw * 8] = *(const uint4*)&Wtg[r * 128 + cw * 8];
  }
#pragma unroll
  for (int q = 0; q < 4; ++q) {
    int f = tid + 256 * q;
    int r = f >> 4, cw = f & 15;
    uint4 v = make_uint4(0u, 0u, 0u, 0u);
    if (row0 + r < nrows) v = *(const uint4*)&h[(size_t)(row0 + r) * 128 + cw * 8];
    *(uint4*)&As[r][cw * 8] = v;
  }
  __syncthreads();
  const int wid = tid >> 6, lane = tid & 63;
  const int fr = lane & 15, fg = lane >> 4;
  f32x4 acc[8];
#pragma unroll
  for (int nn = 0; nn < 8; ++nn) acc[nn] = (f32x4){0.f, 0.f, 0.f, 0.f};
#pragma unroll
  for (int ks = 0; ks < 4; ++ks) {
    const int kb = ks * 32 + fg * 8;
    bf16x8 a = *(const bf16x8*)&As[wid * 16 + fr][kb];
#pragma unroll
    for (int nn = 0; nn < 8; ++nn) {
      bf16x8 b = *(const bf16x8*)&Bs[nn * 16 + fr][kb];
      acc[nn] = __builtin_amdgcn_mfma_f32_16x16x32_bf16(a, b, acc[nn], 0, 0, 0);
    }
  }
  const int r0 = row0 + wid * 16 + fg * 4;
  float dv[4];
#pragma unroll
  for (int i = 0; i < 4; ++i)
    dv[i] = (r0 + i < nrows) ? rsqrtf((float)deg[r0 + i] + 1.0f) : 0.f;
#pragma unroll
  for (int nn = 0; nn < 8; ++nn) {
    const int cn = nn * 16 + fr;
#pragma unroll
    for (int i = 0; i < 4; ++i) {
      const int rr = r0 + i;
      if (rr < nrows) xws[(size_t)rr * 128 + cn] = f2b(acc[nn][i] * dv[i]);
    }
  }
}

// ---------------- L4: per-bucket fine sort -> srcrow CSR + P ---------------
// P[node] = END offset of node's segment (seg = [P[c-1], P[c]), P[-1] := 0).
__global__ __launch_bounds__(256) void k_sort2(const uint* __restrict__ ebuf,
                                               const int* __restrict__ Hs,
                                               int* __restrict__ srcrow,
                                               int* __restrict__ P,
                                               int n) {
  __shared__ int cnt[128];
  __shared__ int lstart[128];
  __shared__ int cnt2[128];
  __shared__ int sd[256];
  const int tid = threadIdx.x;
  if (tid < 128) { cnt[tid] = 0; cnt2[tid] = 0; }
  __syncthreads();
  const int b = blockIdx.x;
  const int start = Hs[b];
  const int end = Hs[b + 1];
  for (int i = start + tid; i < end; i += 256)
    atomicAdd(&cnt[ebuf[i] >> 16], 1);
  __syncthreads();
  const int cv = (tid < 128) ? cnt[tid] : 0;
  sd[tid] = cv;
  __syncthreads();
  for (int off = 1; off < 256; off <<= 1) {
    int u = (tid >= off) ? sd[tid - off] : 0;
    __syncthreads();
    sd[tid] += u;
    __syncthreads();
  }
  if (tid < 128) {
    const int ex = sd[tid] - cv;
    lstart[tid] = ex;
    const int node = b * 128 + tid;
    if (node < n) P[node] = start + ex + cv;
  }
  __syncthreads();
  for (int i = start + tid; i < end; i += 256) {
    const uint v = ebuf[i];
    const int c = v >> 16;
    const int rk = atomicAdd(&cnt2[c], 1);
    srcrow[start + lstart[c] + rk] = (int)(v & 0xFFFFu);
  }
}

// ---------------- L5: fused aggregate + classifier (R8-style gather) -------
// 512 threads / 32 nodes per block. Wave-per-node dynamic queue; lane owns
// 2 cols; 4-edge unroll. Then 6 waves do 32x128x48 MFMA.
__global__ __launch_bounds__(512) void k_aggout(const int* __restrict__ P,
                                                const int* __restrict__ srcrow,
                                                const ushort* __restrict__ xws,
                                                const int* __restrict__ deg,
                                                const float* __restrict__ b_gcn,
                                                const ushort* __restrict__ Wtc,
                                                const float* __restrict__ bc,
                                                float* __restrict__ out, int n) {
  __shared__ ushort ts[32][136];
  __shared__ ushort Bs[48][136];
  __shared__ int nextn;
  const int tid = threadIdx.x;
#pragma unroll
  for (int q = 0; q < 2; ++q) {
    int f = tid + 512 * q;
    if (f < 768) {
      int r = f >> 4, cw = f & 15;
      *(uint4*)&Bs[r][cw * 8] = *(const uint4*)&Wtc[r * 128 + cw * 8];
    }
  }
  if (tid == 0) nextn = 0;
  __syncthreads();

  const int wid = tid >> 6, lane = tid & 63;
  const int row0 = blockIdx.x * 32;
  const size_t off = (size_t)lane * 2;
  const float2 bg = *(const float2*)&b_gcn[lane * 2];

  for (;;) {
    int idx;
    if (lane == 0) idx = atomicAdd(&nextn, 1);
    idx = __shfl(idx, 0);
    if (idx >= 32) break;
    const int c = row0 + idx;
    ushort2 o = make_ushort2(0, 0);
    if (c < n) {
      const int begin = (c == 0) ? 0 : P[c - 1];
      const int end = P[c];
      uint s = *(const uint*)&xws[(size_t)c * 128 + off];  // self (pre-scaled)
      float ax = b2f_lo(s), ay = b2f_hi(s);
      int e = begin;
      for (; e + 4 <= end; e += 4) {
        int r0 = srcrow[e], r1 = srcrow[e + 1], r2 = srcrow[e + 2], r3 = srcrow[e + 3];
        uint v0 = *(const uint*)&xws[(size_t)r0 * 128 + off];
        uint v1 = *(const uint*)&xws[(size_t)r1 * 128 + off];
        uint v2 = *(const uint*)&xws[(size_t)r2 * 128 + off];
        uint v3 = *(const uint*)&xws[(size_t)r3 * 128 + off];
        ax += (b2f_lo(v0) + b2f_lo(v1)) + (b2f_lo(v2) + b2f_lo(v3));
        ay += (b2f_hi(v0) + b2f_hi(v1)) + (b2f_hi(v2) + b2f_hi(v3));
      }
      for (; e < end; ++e) {
        uint v = *(const uint*)&xws[(size_t)srcrow[e] * 128 + off];
        ax += b2f_lo(v);
        ay += b2f_hi(v);
      }
      const float dc = rsqrtf((float)deg[c] + 1.0f);
      o.x = f2b(fmaxf(fmaf(dc, ax, bg.x), 0.f));
      o.y = f2b(fmaxf(fmaf(dc, ay, bg.y), 0.f));
    }
    *(ushort2*)&ts[idx][off] = o;
  }
  __syncthreads();

  // out = ts @ Wtc^T + bc : 2 row-blocks x 3 col-blocks = 6 MFMA tiles
  if (wid < 6) {
    const int rb = wid & 1, nb = wid >> 1;
    const int fr = lane & 15, fg = lane >> 4;
    f32x4 acc = (f32x4){0.f, 0.f, 0.f, 0.f};
#pragma unroll
    for (int ks = 0; ks < 4; ++ks) {
      const int kb = ks * 32 + fg * 8;
      bf16x8 aa = *(const bf16x8*)&ts[rb * 16 + fr][kb];
      bf16x8 bb = *(const bf16x8*)&Bs[nb * 16 + fr][kb];
      acc = __builtin_amdgcn_mfma_f32_16x16x32_bf16(aa, bb, acc, 0, 0, 0);
    }
    const int cn = nb * 16 + fr;
    if (cn < 40) {
      const float bv = bc[cn];
      const int r0 = row0 + rb * 16 + fg * 4;
#pragma unroll
      for (int i = 0; i < 4; ++i) {
        const int rr = r0 + i;
        if (rr < n) out[(size_t)rr * 40 + cn] = acc[i] + bv;
      }
    }
  }
}

extern "C" void kernel_launch(void* const* d_in, const int* in_sizes, int n_in,
                              void* d_out, int out_size, void* d_ws, size_t ws_size,
                              hipStream_t stream) {
  const float* x     = (const float*)d_in[0];
  const int*   ei    = (const int*)d_in[1];
  const float* W_in  = (const float*)d_in[2];
  const float* b_in  = (const float*)d_in[3];
  const float* W_gcn = (const float*)d_in[4];
  const float* b_gcn = (const float*)d_in[5];
  const float* W_cls = (const float*)d_in[6];
  const float* b_cls = (const float*)d_in[7];
  float* out = (float*)d_out;

  const int N = in_sizes[0] / 128;
  const int E = in_sizes[1] / 2;
  const int* row = ei;
  const int* col = ei + E;

  const int sortb = (E + CH_MAX - 1) / CH_MAX;   // 128 for E=600000
  const int chunk = (E + sortb - 1) / sortb;      // <= CH_MAX
  const int nbuck = (N + 127) >> 7;               // 391
  const int zb    = (N + 1023) / 1024;            // deg-zero blocks

  // d_ws layout (~31.3 MB)
  ushort* h      = (ushort*)d_ws;                 // N*128 bf16
  ushort* xws    = h + (size_t)N * 128;           // N*128 bf16
  ushort* Wti    = xws + (size_t)N * 128;         // 128x128
  ushort* Wtg    = Wti + 128 * 128;               // 128x128
  ushort* Wtc    = Wtg + 128 * 128;               // 48x128 zero-padded
  uint*   ebuf   = (uint*)(Wtc + 48 * 128);       // E
  int*    srcrow = (int*)(ebuf + E);              // E
  int*    H2     = srcrow + E;                    // NBUCK*sortb
  int*    Hs     = H2 + NBUCK * sortb;            // NBUCK+1
  int*    cursor = Hs + NBUCK + 1;                // NBUCK
  int*    deg    = cursor + NBUCK;                // N
  int*    P      = deg + N;                       // N

  // L1: weight prep || coarse chist || zero deg
  k_prep_chist_zero<<<PREP_BLKS + sortb + zb, 256, 0, stream>>>(
      W_in, W_gcn, W_cls, Wti, Wtg, Wtc, col, H2, deg, E, chunk, sortb, N);

  // L2: bucket scan || deg histogram || GEMM1 (h = relu(x@W_in+b_in))
  k_scan_hist_gemm1<<<1 + DH + (N + 127) / 128, 512, 0, stream>>>(
      H2, Hs, cursor, sortb, col, deg, E, x, Wti, b_in, h, N, N);

  // L3: reorder || GEMM2 (xws = dinv[r]*(h@W_gcn))
  k_reorder_gemm2<<<sortb + (N + 63) / 64, 256, 0, stream>>>(
      row, col, Hs, cursor, ebuf, E, chunk, sortb, h, Wtg, deg, xws, N);

  // L4: per-bucket fine sort -> srcrow CSR + P
  k_sort2<<<nbuck, 256, 0, stream>>>(ebuf, Hs, srcrow, P, N);

  // L5: out = relu(dinv[c]*(sum xws[r] + xws[c]) + b_gcn) @ W_cls + b_cls
  k_aggout<<<(N + 31) / 32, 512, 0, stream>>>(P, srcrow, xws, deg, b_gcn,
                                              Wtc, b_cls, out, N);
}

// Round 13
// 89.551 us; speedup vs baseline: 1.2657x; 1.2657x over previous
//
#include <hip/hip_runtime.h>

// ---------------------------------------------------------------------------
// PYG_GCN: y = relu(x@W_in+b_in) -> GCNConv(W_gcn,b_gcn) -> relu -> @W_cls+b_cls
// N=50000, E=600000, D=128, C=40.
// R13 = R9 pipeline (dinv from sort's LDS counts, NO global deg-hist) +
//   - L4 sort-only (scale pass removed; dinv applied per-edge in gather fma)
//   - L5 quarter-wave uint4 gather (won R11-vs-R12 A/B)
//   L1 prep||chist -> L2 scan||GEMM1 -> L3 reorder||GEMM2(unscaled)
//   -> L4 sort+P+dinv -> L5 agg(fma dinv)+out
// ---------------------------------------------------------------------------

typedef __bf16 bf16x8 __attribute__((ext_vector_type(8)));
typedef float f32x4 __attribute__((ext_vector_type(4)));

#define NBUCK 512      // bucket = col>>7; used 0..390 for N=50000
#define CH_MAX 4704    // max edges per sort-chunk block
#define PREP_BLKS 152  // 38912 weight elements / 256

__device__ __forceinline__ ushort f2b(float f) {  // fp32 -> bf16 RNE
  uint u = __float_as_uint(f);
  return (ushort)((u + 0x7FFFu + ((u >> 16) & 1u)) >> 16);
}
__device__ __forceinline__ float b2f_lo(uint u) { return __uint_as_float(u << 16); }
__device__ __forceinline__ float b2f_hi(uint u) { return __uint_as_float(u & 0xFFFF0000u); }

__device__ __forceinline__ void acc8s(float* a, uint4 v, float d) {
  a[0] = fmaf(d, b2f_lo(v.x), a[0]); a[1] = fmaf(d, b2f_hi(v.x), a[1]);
  a[2] = fmaf(d, b2f_lo(v.y), a[2]); a[3] = fmaf(d, b2f_hi(v.y), a[3]);
  a[4] = fmaf(d, b2f_lo(v.z), a[4]); a[5] = fmaf(d, b2f_hi(v.z), a[5]);
  a[6] = fmaf(d, b2f_lo(v.w), a[6]); a[7] = fmaf(d, b2f_hi(v.w), a[7]);
}

// ---------------- L1: weight prep (blocks 0..151) || coarse chist ----------
// H2 bucket-major: H2[b*sortb + chunk_blk] (pure stores, no zeroing).
__global__ __launch_bounds__(256) void k_prep_chist(const float* __restrict__ Wi,
                                                    const float* __restrict__ Wg,
                                                    const float* __restrict__ Wc,
                                                    ushort* __restrict__ Ti,
                                                    ushort* __restrict__ Tg,
                                                    ushort* __restrict__ Tc,
                                                    const int* __restrict__ col,
                                                    int* __restrict__ H2,
                                                    int E, int chunk, int sortb) {
  __shared__ int hist[NBUCK];
  const int tid = threadIdx.x;
  if (blockIdx.x < PREP_BLKS) {
    int idx = blockIdx.x * 256 + tid;
    if (idx < 16384) {
      int c = idx >> 7, k = idx & 127;
      Ti[c * 128 + k] = f2b(Wi[k * 128 + c]);
    } else if (idx < 32768) {
      int j = idx - 16384;
      int c = j >> 7, k = j & 127;
      Tg[c * 128 + k] = f2b(Wg[k * 128 + c]);
    } else if (idx < 38912) {
      int j = idx - 32768;
      int c = j >> 7, k = j & 127;
      Tc[c * 128 + k] = (c < 40) ? f2b(Wc[k * 40 + c]) : (ushort)0;
    }
    return;
  }
  const int blk = blockIdx.x - PREP_BLKS;
  for (int b = tid; b < NBUCK; b += 256) hist[b] = 0;
  __syncthreads();
  const int e0 = blk * chunk;
  const int cnt = min(chunk, E - e0);
  for (int i = tid; i < cnt; i += 256)
    atomicAdd(&hist[((unsigned)col[e0 + i]) >> 7], 1);
  __syncthreads();
  for (int b = tid; b < NBUCK; b += 256)
    H2[b * sortb + blk] = hist[b];
}

// ---------------- L2: block 0 = bucket scan; blocks 1.. = GEMM1 ------------
// GEMM1: h = relu(x @ W_in + b_in), 128-row tiles, 8 waves.
__global__ __launch_bounds__(512) void k_scan_gemm1(const int* __restrict__ H2,
                                                    int* __restrict__ Hs,
                                                    int* __restrict__ cursor,
                                                    int sortb,
                                                    const float* __restrict__ x,
                                                    const ushort* __restrict__ Wti,
                                                    const float* __restrict__ b_in,
                                                    ushort* __restrict__ h, int nrows) {
  __shared__ __align__(16) char smem[69632];
  const int tid = threadIdx.x;
  if (blockIdx.x == 0) {
    int* sd = (int*)smem;  // 512 ints
    int s = 0;
    const int4* p = (const int4*)&H2[tid * sortb];
    for (int j = 0; j < sortb / 4; ++j) { int4 v = p[j]; s += v.x + v.y + v.z + v.w; }
    sd[tid] = s;
    __syncthreads();
    for (int off = 1; off < 512; off <<= 1) {
      int u = (tid >= off) ? sd[tid - off] : 0;
      __syncthreads();
      sd[tid] += u;
      __syncthreads();
    }
    Hs[tid] = sd[tid] - s;          // exclusive
    if (tid == 511) Hs[NBUCK] = sd[511];
    cursor[tid] = 0;
    return;
  }
  ushort (*As)[136] = (ushort(*)[136])smem;                    // 128 rows
  ushort (*Bs)[136] = (ushort(*)[136])(smem + 128 * 136 * 2);  // 128 rows
  const int row0 = (blockIdx.x - 1) * 128;
#pragma unroll
  for (int q = 0; q < 4; ++q) {
    int f = tid + 512 * q;
    int r = f >> 4, cw = f & 15;
    *(uint4*)&Bs[r][cw * 8] = *(const uint4*)&Wti[r * 128 + cw * 8];
  }
#pragma unroll
  for (int q = 0; q < 8; ++q) {
    int f = tid + 512 * q;
    int r = f >> 5, kc = f & 31;
    float4 v = make_float4(0.f, 0.f, 0.f, 0.f);
    if (row0 + r < nrows) v = *(const float4*)&x[(size_t)(row0 + r) * 128 + kc * 4];
    ushort4 o;
    o.x = f2b(v.x); o.y = f2b(v.y); o.z = f2b(v.z); o.w = f2b(v.w);
    *(ushort4*)&As[r][kc * 4] = o;
  }
  __syncthreads();

  const int wid = tid >> 6, lane = tid & 63;
  const int fr = lane & 15, fg = lane >> 4;
  f32x4 acc[8];
#pragma unroll
  for (int n = 0; n < 8; ++n) acc[n] = (f32x4){0.f, 0.f, 0.f, 0.f};
#pragma unroll
  for (int ks = 0; ks < 4; ++ks) {
    const int kb = ks * 32 + fg * 8;
    bf16x8 a = *(const bf16x8*)&As[wid * 16 + fr][kb];
#pragma unroll
    for (int n = 0; n < 8; ++n) {
      bf16x8 b = *(const bf16x8*)&Bs[n * 16 + fr][kb];
      acc[n] = __builtin_amdgcn_mfma_f32_16x16x32_bf16(a, b, acc[n], 0, 0, 0);
    }
  }
  const int r0 = row0 + wid * 16 + fg * 4;
#pragma unroll
  for (int n = 0; n < 8; ++n) {
    const int cn = n * 16 + fr;
    const float bv = b_in[cn];
#pragma unroll
    for (int i = 0; i < 4; ++i) {
      const int rr = r0 + i;
      if (rr < nrows) h[(size_t)rr * 128 + cn] = f2b(fmaxf(acc[n][i] + bv, 0.f));
    }
  }
}

// ---------------- L3: blocks [0,sortb) = reorder; rest = GEMM2 -------------
// ebuf record: (c_local<<16) | row. GEMM2: xws = h @ W_gcn (UNSCALED).
__global__ __launch_bounds__(256) void k_reorder_gemm2(const int* __restrict__ row,
                                                       const int* __restrict__ col,
                                                       const int* __restrict__ Hs,
                                                       int* __restrict__ cursor,
                                                       uint* __restrict__ ebuf,
                                                       int E, int chunk, int sortb,
                                                       const ushort* __restrict__ h,
                                                       const ushort* __restrict__ Wtg,
                                                       ushort* __restrict__ xws,
                                                       int nrows) {
  __shared__ __align__(16) char smem[52224];
  const int tid = threadIdx.x;
  if (blockIdx.x < sortb) {
    int* hist   = (int*)smem;              // NBUCK
    int* lstart = hist + NBUCK;            // NBUCK
    int* cnt2   = lstart + NBUCK;          // NBUCK
    int* obase  = cnt2 + NBUCK;            // NBUCK
    uint* data  = (uint*)(obase + NBUCK);  // CH_MAX
    int* gpos   = (int*)(data + CH_MAX);   // CH_MAX
    int* sd     = gpos + CH_MAX;           // 256
    for (int b = tid; b < NBUCK; b += 256) { hist[b] = 0; cnt2[b] = 0; }
    __syncthreads();
    const int e0 = blockIdx.x * chunk;
    const int cnt = min(chunk, E - e0);
    for (int i = tid; i < cnt; i += 256)
      atomicAdd(&hist[((unsigned)col[e0 + i]) >> 7], 1);
    __syncthreads();
    const int h0 = hist[2 * tid], h1 = hist[2 * tid + 1];
    const int ps = h0 + h1;
    sd[tid] = ps;
    __syncthreads();
    for (int off = 1; off < 256; off <<= 1) {
      int u = (tid >= off) ? sd[tid - off] : 0;
      __syncthreads();
      sd[tid] += u;
      __syncthreads();
    }
    const int ex = sd[tid] - ps;
    lstart[2 * tid] = ex;
    lstart[2 * tid + 1] = ex + h0;
    obase[2 * tid]     = Hs[2 * tid]     + (h0 ? atomicAdd(&cursor[2 * tid], h0) : 0);
    obase[2 * tid + 1] = Hs[2 * tid + 1] + (h1 ? atomicAdd(&cursor[2 * tid + 1], h1) : 0);
    __syncthreads();
    for (int i = tid; i < cnt; i += 256) {
      const int c = col[e0 + i], r = row[e0 + i];
      const int b = ((unsigned)c) >> 7;
      const int rk = atomicAdd(&cnt2[b], 1);
      const int slot = lstart[b] + rk;
      data[slot] = ((uint)(c & 127) << 16) | (uint)r;
      gpos[slot] = obase[b] + rk;
    }
    __syncthreads();
    for (int i = tid; i < cnt; i += 256)
      ebuf[gpos[i]] = data[i];
    return;
  }
  // GEMM2: 64-row tile, 4 waves
  ushort (*As)[136] = (ushort(*)[136])smem;                   // 64 rows
  ushort (*Bs)[136] = (ushort(*)[136])(smem + 64 * 136 * 2);  // 128 rows
  const int row0 = (blockIdx.x - sortb) * 64;
#pragma unroll
  for (int q = 0; q < 8; ++q) {
    int f = tid + 256 * q;
    int r = f >> 4, cw = f & 15;
    *(uint4*)&Bs[r][cw * 8] = *(const uint4*)&Wtg[r * 128 + cw * 8];
  }
#pragma unroll
  for (int q = 0; q < 4; ++q) {
    int f = tid + 256 * q;
    int r = f >> 4, cw = f & 15;
    uint4 v = make_uint4(0u, 0u, 0u, 0u);
    if (row0 + r < nrows) v = *(const uint4*)&h[(size_t)(row0 + r) * 128 + cw * 8];
    *(uint4*)&As[r][cw * 8] = v;
  }
  __syncthreads();
  const int wid = tid >> 6, lane = tid & 63;
  const int fr = lane & 15, fg = lane >> 4;
  f32x4 acc[8];
#pragma unroll
  for (int n = 0; n < 8; ++n) acc[n] = (f32x4){0.f, 0.f, 0.f, 0.f};
#pragma unroll
  for (int ks = 0; ks < 4; ++ks) {
    const int kb = ks * 32 + fg * 8;
    bf16x8 a = *(const bf16x8*)&As[wid * 16 + fr][kb];
#pragma unroll
    for (int n = 0; n < 8; ++n) {
      bf16x8 b = *(const bf16x8*)&Bs[n * 16 + fr][kb];
      acc[n] = __builtin_amdgcn_mfma_f32_16x16x32_bf16(a, b, acc[n], 0, 0, 0);
    }
  }
  const int r0 = row0 + wid * 16 + fg * 4;
#pragma unroll
  for (int n = 0; n < 8; ++n) {
    const int cn = n * 16 + fr;
#pragma unroll
    for (int i = 0; i < 4; ++i) {
      const int rr = r0 + i;
      if (rr < nrows) xws[(size_t)rr * 128 + cn] = f2b(acc[n][i]);
    }
  }
}

// ---------------- L4: per-bucket fine sort -> srcrow CSR + P + dinv --------
// P[node] = END offset (seg = [P[c-1], P[c]), P[-1] := 0). Scatter confined
// to the bucket's private window. dinv from LDS counts (no global deg-hist).
__global__ __launch_bounds__(256) void k_sort2(const uint* __restrict__ ebuf,
                                               const int* __restrict__ Hs,
                                               int* __restrict__ srcrow,
                                               int* __restrict__ P,
                                               float* __restrict__ dinv,
                                               int n) {
  __shared__ int cnt[128];
  __shared__ int lstart[128];
  __shared__ int cnt2[128];
  __shared__ int sd[256];
  const int tid = threadIdx.x;
  if (tid < 128) { cnt[tid] = 0; cnt2[tid] = 0; }
  __syncthreads();
  const int b = blockIdx.x;
  const int start = Hs[b];
  const int end = Hs[b + 1];
  for (int i = start + tid; i < end; i += 256)
    atomicAdd(&cnt[ebuf[i] >> 16], 1);
  __syncthreads();
  const int cv = (tid < 128) ? cnt[tid] : 0;
  sd[tid] = cv;
  __syncthreads();
  for (int off = 1; off < 256; off <<= 1) {
    int u = (tid >= off) ? sd[tid - off] : 0;
    __syncthreads();
    sd[tid] += u;
    __syncthreads();
  }
  if (tid < 128) {
    const int ex = sd[tid] - cv;
    lstart[tid] = ex;
    const int node = b * 128 + tid;
    if (node < n) {
      P[node] = start + ex + cv;
      dinv[node] = rsqrtf((float)cv + 1.0f);
    }
  }
  __syncthreads();
  for (int i = start + tid; i < end; i += 256) {
    const uint v = ebuf[i];
    const int c = v >> 16;
    const int rk = atomicAdd(&cnt2[c], 1);
    srcrow[start + lstart[c] + rk] = (int)(v & 0xFFFFu);
  }
}

// ---------------- L5: fused aggregate + classifier -------------------------
// 512 threads / 32 nodes per block. Quarter-wave uint4 gather with per-edge
// dinv[r] fma scaling (xws unscaled). Cross-quarter shfl_xor reduce; then
// 6 waves do 32x128x48 MFMA.
__global__ __launch_bounds__(512) void k_aggout(const int* __restrict__ P,
                                                const int* __restrict__ srcrow,
                                                const ushort* __restrict__ xws,
                                                const float* __restrict__ dinv,
                                                const float* __restrict__ b_gcn,
                                                const ushort* __restrict__ Wtc,
                                                const float* __restrict__ bc,
                                                float* __restrict__ out, int n) {
  __shared__ ushort ts[32][136];
  __shared__ ushort Bs[48][136];
  __shared__ int nextn;
  const int tid = threadIdx.x;
#pragma unroll
  for (int q = 0; q < 2; ++q) {
    int f = tid + 512 * q;
    if (f < 768) {
      int r = f >> 4, cw = f & 15;
      *(uint4*)&Bs[r][cw * 8] = *(const uint4*)&Wtc[r * 128 + cw * 8];
    }
  }
  if (tid == 0) nextn = 0;
  __syncthreads();

  const int wid = tid >> 6, lane = tid & 63;
  const int qt = lane >> 4, lq = lane & 15;   // quarter / lane-in-quarter
  const int row0 = blockIdx.x * 32;
  const size_t coff = (size_t)lq * 8;         // 8 cols per lane

  float bg[8];
#pragma unroll
  for (int j = 0; j < 8; ++j) bg[j] = b_gcn[lq * 8 + j];

  for (;;) {
    int idx;
    if (lane == 0) idx = atomicAdd(&nextn, 1);
    idx = __shfl(idx, 0);
    if (idx >= 32) break;
    const int c = row0 + idx;
    if (c < n) {
      const int begin = (c == 0) ? 0 : P[c - 1];
      const int end = P[c];
      float a[8];
#pragma unroll
      for (int j = 0; j < 8; ++j) a[j] = 0.f;
      int e = begin;
      for (; e + 8 <= end; e += 8) {   // 8 edges per iteration (2 per quarter)
        const int r0 = srcrow[e + qt];
        const int r1 = srcrow[e + 4 + qt];
        const float d0 = dinv[r0], d1 = dinv[r1];
        const uint4 v0 = *(const uint4*)&xws[(size_t)r0 * 128 + coff];
        const uint4 v1 = *(const uint4*)&xws[(size_t)r1 * 128 + coff];
        acc8s(a, v0, d0);
        acc8s(a, v1, d1);
      }
      for (; e < end; e += 4) {        // predicated tail, up to 4 edges/iter
        if (e + qt < end) {
          const int r = srcrow[e + qt];
          const float d = dinv[r];
          const uint4 v = *(const uint4*)&xws[(size_t)r * 128 + coff];
          acc8s(a, v, d);
        }
      }
      // cross-quarter reduction: lanes lq, lq+16, lq+32, lq+48 -> total
#pragma unroll
      for (int j = 0; j < 8; ++j) {
        a[j] += __shfl_xor(a[j], 16);
        a[j] += __shfl_xor(a[j], 32);
      }
      if (qt == 0) {
        const uint4 sv = *(const uint4*)&xws[(size_t)c * 128 + coff];  // self
        const float dc = dinv[c];
        // add self term dc*xw[c], then t = relu(dc*total + bias)
        acc8s(a, sv, dc);
        const float t0 = fmaxf(fmaf(dc, a[0], bg[0]), 0.f);
        const float t1 = fmaxf(fmaf(dc, a[1], bg[1]), 0.f);
        const float t2 = fmaxf(fmaf(dc, a[2], bg[2]), 0.f);
        const float t3 = fmaxf(fmaf(dc, a[3], bg[3]), 0.f);
        const float t4 = fmaxf(fmaf(dc, a[4], bg[4]), 0.f);
        const float t5 = fmaxf(fmaf(dc, a[5], bg[5]), 0.f);
        const float t6 = fmaxf(fmaf(dc, a[6], bg[6]), 0.f);
        const float t7 = fmaxf(fmaf(dc, a[7], bg[7]), 0.f);
        uint4 o;
        o.x = ((uint)f2b(t1) << 16) | f2b(t0);
        o.y = ((uint)f2b(t3) << 16) | f2b(t2);
        o.z = ((uint)f2b(t5) << 16) | f2b(t4);
        o.w = ((uint)f2b(t7) << 16) | f2b(t6);
        *(uint4*)&ts[idx][coff] = o;
      }
    } else if (qt == 0) {
      *(uint4*)&ts[idx][coff] = make_uint4(0u, 0u, 0u, 0u);
    }
  }
  __syncthreads();

  // out = ts @ Wtc^T + bc : 2 row-blocks x 3 col-blocks = 6 MFMA tiles
  if (wid < 6) {
    const int rb = wid & 1, nb = wid >> 1;
    const int fr = lane & 15, fg = lane >> 4;
    f32x4 acc = (f32x4){0.f, 0.f, 0.f, 0.f};
#pragma unroll
    for (int ks = 0; ks < 4; ++ks) {
      const int kb = ks * 32 + fg * 8;
      bf16x8 aa = *(const bf16x8*)&ts[rb * 16 + fr][kb];
      bf16x8 bb = *(const bf16x8*)&Bs[nb * 16 + fr][kb];
      acc = __builtin_amdgcn_mfma_f32_16x16x32_bf16(aa, bb, acc, 0, 0, 0);
    }
    const int cn = nb * 16 + fr;
    if (cn < 40) {
      const float bv = bc[cn];
      const int r0 = row0 + rb * 16 + fg * 4;
#pragma unroll
      for (int i = 0; i < 4; ++i) {
        const int rr = r0 + i;
        if (rr < n) out[(size_t)rr * 40 + cn] = acc[i] + bv;
      }
    }
  }
}

extern "C" void kernel_launch(void* const* d_in, const int* in_sizes, int n_in,
                              void* d_out, int out_size, void* d_ws, size_t ws_size,
                              hipStream_t stream) {
  const float* x     = (const float*)d_in[0];
  const int*   ei    = (const int*)d_in[1];
  const float* W_in  = (const float*)d_in[2];
  const float* b_in  = (const float*)d_in[3];
  const float* W_gcn = (const float*)d_in[4];
  const float* b_gcn = (const float*)d_in[5];
  const float* W_cls = (const float*)d_in[6];
  const float* b_cls = (const float*)d_in[7];
  float* out = (float*)d_out;

  const int N = in_sizes[0] / 128;
  const int E = in_sizes[1] / 2;
  const int* row = ei;
  const int* col = ei + E;

  const int sortb = (E + CH_MAX - 1) / CH_MAX;   // 128 for E=600000
  const int chunk = (E + sortb - 1) / sortb;      // <= CH_MAX
  const int nbuck = (N + 127) >> 7;               // 391

  // d_ws layout (~31.5 MB)
  ushort* h      = (ushort*)d_ws;                 // N*128 bf16
  ushort* xws    = h + (size_t)N * 128;           // N*128 bf16
  ushort* Wti    = xws + (size_t)N * 128;         // 128x128
  ushort* Wtg    = Wti + 128 * 128;               // 128x128
  ushort* Wtc    = Wtg + 128 * 128;               // 48x128 zero-padded
  uint*   ebuf   = (uint*)(Wtc + 48 * 128);       // E
  int*    srcrow = (int*)(ebuf + E);              // E
  int*    H2     = srcrow + E;                    // NBUCK*sortb
  int*    Hs     = H2 + NBUCK * sortb;            // NBUCK+1
  int*    cursor = Hs + NBUCK + 1;                // NBUCK
  int*    P      = cursor + NBUCK;                // N
  float*  dinv   = (float*)(P + N);               // N

  // L1: weight prep || coarse chist
  k_prep_chist<<<PREP_BLKS + sortb, 256, 0, stream>>>(W_in, W_gcn, W_cls,
                                                      Wti, Wtg, Wtc,
                                                      col, H2, E, chunk, sortb);
  // L2: bucket scan || GEMM1 (h = relu(x@W_in+b_in))
  k_scan_gemm1<<<1 + (N + 127) / 128, 512, 0, stream>>>(H2, Hs, cursor, sortb,
                                                        x, Wti, b_in, h, N);
  // L3: reorder || GEMM2 (xws = h@W_gcn, unscaled)
  k_reorder_gemm2<<<sortb + (N + 63) / 64, 256, 0, stream>>>(row, col, Hs, cursor,
                                                             ebuf, E, chunk, sortb,
                                                             h, Wtg, xws, N);
  // L4: fine sort -> srcrow/P/dinv (no xws traffic)
  k_sort2<<<nbuck, 256, 0, stream>>>(ebuf, Hs, srcrow, P, dinv, N);

  // L5: out = relu(dinv[c]*(sum dinv[r]*xw[r] + dinv[c]*xw[c]) + b_gcn) @ W_cls + b_cls
  k_aggout<<<(N + 31) / 32, 512, 0, stream>>>(P, srcrow, xws, dinv, b_gcn,
                                              Wtc, b_cls, out, N);
}

// Round 14
// 79.640 us; speedup vs baseline: 1.4233x; 1.1244x over previous
//
#include <hip/hip_runtime.h>

// ---------------------------------------------------------------------------
// PYG_GCN: y = relu(x@W_in+b_in) -> GCNConv(W_gcn,b_gcn) -> relu -> @W_cls+b_cls
// N=50000, E=600000, D=128, C=40.
// R14: all-512-thread pipeline with split GEMM halves so every sort stage
// hides under GEMM work; aggout stages its contiguous srcrow window + P
// boundaries in LDS (cuts per-node startup latency).
//   L1 prep||chist -> L2 scan||G1a -> L3 reorder||G1b||G2a
//   -> L4 sort2||G2b -> L5 aggout
// ---------------------------------------------------------------------------

typedef __bf16 bf16x8 __attribute__((ext_vector_type(8)));
typedef float f32x4 __attribute__((ext_vector_type(4)));

#define NBUCK 512      // bucket = col>>7; used 0..390 for N=50000
#define CH_MAX 4704    // max edges per sort-chunk block
#define PREP_BLKS 76   // 38912 weight elements / 512
#define SCAP 1024      // aggout LDS edge window (32 nodes: mean 384, +32 sigma)

__device__ __forceinline__ ushort f2b(float f) {  // fp32 -> bf16 RNE
  uint u = __float_as_uint(f);
  return (ushort)((u + 0x7FFFu + ((u >> 16) & 1u)) >> 16);
}
__device__ __forceinline__ float b2f_lo(uint u) { return __uint_as_float(u << 16); }
__device__ __forceinline__ float b2f_hi(uint u) { return __uint_as_float(u & 0xFFFF0000u); }

__device__ __forceinline__ void acc8s(float* a, uint4 v, float d) {
  a[0] = fmaf(d, b2f_lo(v.x), a[0]); a[1] = fmaf(d, b2f_hi(v.x), a[1]);
  a[2] = fmaf(d, b2f_lo(v.y), a[2]); a[3] = fmaf(d, b2f_hi(v.y), a[3]);
  a[4] = fmaf(d, b2f_lo(v.z), a[4]); a[5] = fmaf(d, b2f_hi(v.z), a[5]);
  a[6] = fmaf(d, b2f_lo(v.w), a[6]); a[7] = fmaf(d, b2f_hi(v.w), a[7]);
}

// ---------------- shared GEMM tile: 512 threads, 128 rows, K=128 -----------
// O(bf16, 128 cols) = post(A @ Wt^T): Wt bf16 col-major [128][128].
template<bool ABF16, bool RELU, bool BIAS>
__device__ __forceinline__ void gemm_tile_512(const void* __restrict__ Ap,
                                              const ushort* __restrict__ Wt,
                                              const float* __restrict__ bias,
                                              ushort* __restrict__ O,
                                              int nrows, int row0,
                                              char* smem, int tid) {
  ushort (*As)[136] = (ushort(*)[136])smem;                    // 128 rows
  ushort (*Bs)[136] = (ushort(*)[136])(smem + 128 * 136 * 2);  // 128 rows
#pragma unroll
  for (int q = 0; q < 4; ++q) {
    int f = tid + 512 * q;
    int r = f >> 4, cw = f & 15;
    *(uint4*)&Bs[r][cw * 8] = *(const uint4*)&Wt[r * 128 + cw * 8];
  }
  if (ABF16) {
    const ushort* A = (const ushort*)Ap;
#pragma unroll
    for (int q = 0; q < 4; ++q) {
      int f = tid + 512 * q;
      int r = f >> 4, cw = f & 15;
      uint4 v = make_uint4(0u, 0u, 0u, 0u);
      if (row0 + r < nrows) v = *(const uint4*)&A[(size_t)(row0 + r) * 128 + cw * 8];
      *(uint4*)&As[r][cw * 8] = v;
    }
  } else {
    const float* A = (const float*)Ap;
#pragma unroll
    for (int q = 0; q < 8; ++q) {
      int f = tid + 512 * q;
      int r = f >> 5, kc = f & 31;
      float4 v = make_float4(0.f, 0.f, 0.f, 0.f);
      if (row0 + r < nrows) v = *(const float4*)&A[(size_t)(row0 + r) * 128 + kc * 4];
      ushort4 o;
      o.x = f2b(v.x); o.y = f2b(v.y); o.z = f2b(v.z); o.w = f2b(v.w);
      *(ushort4*)&As[r][kc * 4] = o;
    }
  }
  __syncthreads();

  const int wid = tid >> 6, lane = tid & 63;
  const int fr = lane & 15, fg = lane >> 4;
  f32x4 acc[8];
#pragma unroll
  for (int nn = 0; nn < 8; ++nn) acc[nn] = (f32x4){0.f, 0.f, 0.f, 0.f};
#pragma unroll
  for (int ks = 0; ks < 4; ++ks) {
    const int kb = ks * 32 + fg * 8;
    bf16x8 a = *(const bf16x8*)&As[wid * 16 + fr][kb];
#pragma unroll
    for (int nn = 0; nn < 8; ++nn) {
      bf16x8 b = *(const bf16x8*)&Bs[nn * 16 + fr][kb];
      acc[nn] = __builtin_amdgcn_mfma_f32_16x16x32_bf16(a, b, acc[nn], 0, 0, 0);
    }
  }
  const int r0 = row0 + wid * 16 + fg * 4;
#pragma unroll
  for (int nn = 0; nn < 8; ++nn) {
    const int cn = nn * 16 + fr;
    const float bv = BIAS ? bias[cn] : 0.f;
#pragma unroll
    for (int i = 0; i < 4; ++i) {
      const int rr = r0 + i;
      if (rr < nrows) {
        float v = acc[nn][i] + bv;
        if (RELU) v = fmaxf(v, 0.f);
        O[(size_t)rr * 128 + cn] = f2b(v);
      }
    }
  }
}

// ---------------- L1: weight prep [0,76) || coarse chist -------------------
// H2 bucket-major: H2[b*sortb + chunk_blk] (pure stores, no zeroing).
__global__ __launch_bounds__(512) void k_L1_prep_chist(const float* __restrict__ Wi,
                                                       const float* __restrict__ Wg,
                                                       const float* __restrict__ Wc,
                                                       ushort* __restrict__ Ti,
                                                       ushort* __restrict__ Tg,
                                                       ushort* __restrict__ Tc,
                                                       const int* __restrict__ col,
                                                       int* __restrict__ H2,
                                                       int E, int chunk, int sortb) {
  __shared__ int hist[NBUCK];
  const int tid = threadIdx.x;
  if (blockIdx.x < PREP_BLKS) {
    int idx = blockIdx.x * 512 + tid;
    if (idx < 16384) {
      int c = idx >> 7, k = idx & 127;
      Ti[c * 128 + k] = f2b(Wi[k * 128 + c]);
    } else if (idx < 32768) {
      int j = idx - 16384;
      int c = j >> 7, k = j & 127;
      Tg[c * 128 + k] = f2b(Wg[k * 128 + c]);
    } else if (idx < 38912) {
      int j = idx - 32768;
      int c = j >> 7, k = j & 127;
      Tc[c * 128 + k] = (c < 40) ? f2b(Wc[k * 40 + c]) : (ushort)0;
    }
    return;
  }
  const int blk = blockIdx.x - PREP_BLKS;
  if (tid < NBUCK) hist[tid] = 0;
  __syncthreads();
  const int e0 = blk * chunk;
  const int cnt = min(chunk, E - e0);
  for (int i = tid; i < cnt; i += 512)
    atomicAdd(&hist[((unsigned)col[e0 + i]) >> 7], 1);
  __syncthreads();
  if (tid < NBUCK) H2[tid * sortb + blk] = hist[tid];
}

// ---------------- L2: block 0 = bucket scan; blocks 1.. = G1a --------------
__global__ __launch_bounds__(512) void k_L2_scan_g1a(const int* __restrict__ H2,
                                                     int* __restrict__ Hs,
                                                     int* __restrict__ cursor,
                                                     int sortb,
                                                     const float* __restrict__ x,
                                                     const ushort* __restrict__ Wti,
                                                     const float* __restrict__ b_in,
                                                     ushort* __restrict__ h, int nrows) {
  __shared__ __align__(16) char smem[69632];
  const int tid = threadIdx.x;
  if (blockIdx.x == 0) {
    int* sd = (int*)smem;  // 512 ints
    int s = 0;
    const int4* p = (const int4*)&H2[tid * sortb];
    for (int j = 0; j < sortb / 4; ++j) { int4 v = p[j]; s += v.x + v.y + v.z + v.w; }
    sd[tid] = s;
    __syncthreads();
    for (int off = 1; off < 512; off <<= 1) {
      int u = (tid >= off) ? sd[tid - off] : 0;
      __syncthreads();
      sd[tid] += u;
      __syncthreads();
    }
    Hs[tid] = sd[tid] - s;          // exclusive
    if (tid == 511) Hs[NBUCK] = sd[511];
    cursor[tid] = 0;
    return;
  }
  gemm_tile_512<false, true, true>(x, Wti, b_in, h, nrows,
                                   (blockIdx.x - 1) * 128, smem, tid);
}

// ---------------- L3: reorder [0,sortb) || G1b || G2a ----------------------
// ebuf record: (c_local<<16) | row  (row < 65536 since N=50000).
__global__ __launch_bounds__(512) void k_L3_reorder_g1b_g2a(const int* __restrict__ row,
                                                            const int* __restrict__ col,
                                                            const int* __restrict__ Hs,
                                                            int* __restrict__ cursor,
                                                            uint* __restrict__ ebuf,
                                                            int E, int chunk, int sortb,
                                                            const float* __restrict__ x,
                                                            const ushort* __restrict__ Wti,
                                                            const float* __restrict__ b_in,
                                                            const ushort* __restrict__ Wtg,
                                                            ushort* __restrict__ h,
                                                            ushort* __restrict__ xws,
                                                            int nrows) {
  __shared__ __align__(16) char smem[69632];
  const int tid = threadIdx.x;
  const int NT = (nrows + 127) >> 7;
  const int SPLIT = (NT + 1) >> 1;
  if (blockIdx.x < (unsigned)sortb) {
    int* hist   = (int*)smem;              // NBUCK
    int* lstart = hist + NBUCK;            // NBUCK
    int* cnt2   = lstart + NBUCK;          // NBUCK
    int* obase  = cnt2 + NBUCK;            // NBUCK
    uint* data  = (uint*)(obase + NBUCK);  // CH_MAX
    int* gpos   = (int*)(data + CH_MAX);   // CH_MAX
    int* sd     = gpos + CH_MAX;           // 512
    hist[tid] = 0; cnt2[tid] = 0;
    __syncthreads();
    const int e0 = blockIdx.x * chunk;
    const int cnt = min(chunk, E - e0);
    for (int i = tid; i < cnt; i += 512)
      atomicAdd(&hist[((unsigned)col[e0 + i]) >> 7], 1);
    __syncthreads();
    const int h0 = hist[tid];
    sd[tid] = h0;
    __syncthreads();
    for (int off = 1; off < 512; off <<= 1) {
      int u = (tid >= off) ? sd[tid - off] : 0;
      __syncthreads();
      sd[tid] += u;
      __syncthreads();
    }
    lstart[tid] = sd[tid] - h0;
    obase[tid] = Hs[tid] + (h0 ? atomicAdd(&cursor[tid], h0) : 0);
    __syncthreads();
    for (int i = tid; i < cnt; i += 512) {
      const int c = col[e0 + i], r = row[e0 + i];
      const int b = ((unsigned)c) >> 7;
      const int rk = atomicAdd(&cnt2[b], 1);
      const int slot = lstart[b] + rk;
      data[slot] = ((uint)(c & 127) << 16) | (uint)r;
      gpos[slot] = obase[b] + rk;
    }
    __syncthreads();
    for (int i = tid; i < cnt; i += 512)
      ebuf[gpos[i]] = data[i];
    return;
  }
  const int t = blockIdx.x - sortb;
  if (t < NT - SPLIT) {
    // G1b: h rows for tiles [SPLIT, NT)
    gemm_tile_512<false, true, true>(x, Wti, b_in, h, nrows,
                                     (SPLIT + t) * 128, smem, tid);
  } else {
    // G2a: xws rows for tiles [0, SPLIT) (h rows produced by G1a in L2)
    gemm_tile_512<true, false, false>(h, Wtg, nullptr, xws, nrows,
                                      (t - (NT - SPLIT)) * 128, smem, tid);
  }
}

// ---------------- L4: sort2 [0,nbuck) || G2b -------------------------------
// P[node] = END offset (seg = [P[c-1], P[c]), P[-1] := 0).
__global__ __launch_bounds__(512) void k_L4_sort_g2b(const uint* __restrict__ ebuf,
                                                     const int* __restrict__ Hs,
                                                     int* __restrict__ srcrow,
                                                     int* __restrict__ P,
                                                     float* __restrict__ dinv,
                                                     int nbuck,
                                                     const ushort* __restrict__ h,
                                                     const ushort* __restrict__ Wtg,
                                                     ushort* __restrict__ xws,
                                                     int n) {
  __shared__ __align__(16) char smem[69632];
  const int tid = threadIdx.x;
  if (blockIdx.x < (unsigned)nbuck) {
    int* cnt    = (int*)smem;        // 128
    int* lstart = cnt + 128;         // 128
    int* cnt2   = lstart + 128;      // 128
    int* sd     = cnt2 + 128;        // 512
    if (tid < 128) { cnt[tid] = 0; cnt2[tid] = 0; }
    __syncthreads();
    const int b = blockIdx.x;
    const int start = Hs[b];
    const int end = Hs[b + 1];
    for (int i = start + tid; i < end; i += 512)
      atomicAdd(&cnt[ebuf[i] >> 16], 1);
    __syncthreads();
    const int cv = (tid < 128) ? cnt[tid] : 0;
    sd[tid] = cv;
    __syncthreads();
    for (int off = 1; off < 128; off <<= 1) {
      int u = (tid >= off) ? sd[tid - off] : 0;
      __syncthreads();
      sd[tid] += u;
      __syncthreads();
    }
    if (tid < 128) {
      const int ex = sd[tid] - cv;
      lstart[tid] = ex;
      const int node = b * 128 + tid;
      if (node < n) {
        P[node] = start + ex + cv;
        dinv[node] = rsqrtf((float)cv + 1.0f);
      }
    }
    __syncthreads();
    for (int i = start + tid; i < end; i += 512) {
      const uint v = ebuf[i];
      const int c = v >> 16;
      const int rk = atomicAdd(&cnt2[c], 1);
      srcrow[start + lstart[c] + rk] = (int)(v & 0xFFFFu);
    }
    return;
  }
  const int NT = (n + 127) >> 7;
  const int SPLIT = (NT + 1) >> 1;
  const int t = blockIdx.x - nbuck;
  gemm_tile_512<true, false, false>(h, Wtg, nullptr, xws, n,
                                    (SPLIT + t) * 128, smem, tid);
}

// ---------------- L5: fused aggregate + classifier -------------------------
// 512 threads / 32 nodes. Block's srcrow window + P boundaries staged in LDS
// (contiguous since nodes sorted). Quarter-wave uint4 gather with per-edge
// dinv fma; cross-quarter shfl_xor reduce; 6 waves do 32x128x48 MFMA.
__global__ __launch_bounds__(512) void k_aggout(const int* __restrict__ P,
                                                const int* __restrict__ srcrow,
                                                const ushort* __restrict__ xws,
                                                const float* __restrict__ dinv,
                                                const float* __restrict__ b_gcn,
                                                const ushort* __restrict__ Wtc,
                                                const float* __restrict__ bc,
                                                float* __restrict__ out, int n) {
  __shared__ ushort ts[32][136];
  __shared__ ushort Bs[48][136];
  __shared__ int eLds[SCAP];
  __shared__ int pb[33];
  __shared__ int nextn;
  const int tid = threadIdx.x;
  const int row0 = blockIdx.x * 32;
#pragma unroll
  for (int q = 0; q < 2; ++q) {
    int f = tid + 512 * q;
    if (f < 768) {
      int r = f >> 4, cw = f & 15;
      *(uint4*)&Bs[r][cw * 8] = *(const uint4*)&Wtc[r * 128 + cw * 8];
    }
  }
  if (tid < 33) {
    int node = row0 + tid - 1;
    pb[tid] = (node < 0) ? 0 : P[node < n ? node : (n - 1)];
  }
  if (tid == 0) nextn = 0;
  __syncthreads();
  const int sStart = pb[0];
  const int tot = pb[32] - sStart;
  const bool inL = (tot <= SCAP);
  if (inL) {
    for (int i = tid; i < tot; i += 512) eLds[i] = srcrow[sStart + i];
  }
  __syncthreads();

  const int wid = tid >> 6, lane = tid & 63;
  const int qt = lane >> 4, lq = lane & 15;   // quarter / lane-in-quarter
  const size_t coff = (size_t)lq * 8;         // 8 cols per lane

  float bg[8];
#pragma unroll
  for (int j = 0; j < 8; ++j) bg[j] = b_gcn[lq * 8 + j];

  for (;;) {
    int idx;
    if (lane == 0) idx = atomicAdd(&nextn, 1);
    idx = __shfl(idx, 0);
    if (idx >= 32) break;
    const int c = row0 + idx;
    if (c < n) {
      const int len = pb[idx + 1] - pb[idx];
      float a[8];
#pragma unroll
      for (int j = 0; j < 8; ++j) a[j] = 0.f;
      if (inL) {
        const int base = pb[idx] - sStart;
        int e = 0;
        for (; e + 8 <= len; e += 8) {   // 8 edges/iter (2 per quarter)
          const int r0 = eLds[base + e + qt];
          const int r1 = eLds[base + e + 4 + qt];
          const float d0 = dinv[r0], d1 = dinv[r1];
          const uint4 v0 = *(const uint4*)&xws[(size_t)r0 * 128 + coff];
          const uint4 v1 = *(const uint4*)&xws[(size_t)r1 * 128 + coff];
          acc8s(a, v0, d0);
          acc8s(a, v1, d1);
        }
        for (; e < len; e += 4) {        // predicated tail
          if (e + qt < len) {
            const int r = eLds[base + e + qt];
            const float d = dinv[r];
            const uint4 v = *(const uint4*)&xws[(size_t)r * 128 + coff];
            acc8s(a, v, d);
          }
        }
      } else {                           // fallback: global srcrow
        const int base = pb[idx];
        int e = 0;
        for (; e + 8 <= len; e += 8) {
          const int r0 = srcrow[base + e + qt];
          const int r1 = srcrow[base + e + 4 + qt];
          const float d0 = dinv[r0], d1 = dinv[r1];
          const uint4 v0 = *(const uint4*)&xws[(size_t)r0 * 128 + coff];
          const uint4 v1 = *(const uint4*)&xws[(size_t)r1 * 128 + coff];
          acc8s(a, v0, d0);
          acc8s(a, v1, d1);
        }
        for (; e < len; e += 4) {
          if (e + qt < len) {
            const int r = srcrow[base + e + qt];
            const float d = dinv[r];
            const uint4 v = *(const uint4*)&xws[(size_t)r * 128 + coff];
            acc8s(a, v, d);
          }
        }
      }
      // cross-quarter reduction
#pragma unroll
      for (int j = 0; j < 8; ++j) {
        a[j] += __shfl_xor(a[j], 16);
        a[j] += __shfl_xor(a[j], 32);
      }
      if (qt == 0) {
        const uint4 sv = *(const uint4*)&xws[(size_t)c * 128 + coff];  // self
        const float dc = dinv[c];
        acc8s(a, sv, dc);
        const float t0 = fmaxf(fmaf(dc, a[0], bg[0]), 0.f);
        const float t1 = fmaxf(fmaf(dc, a[1], bg[1]), 0.f);
        const float t2 = fmaxf(fmaf(dc, a[2], bg[2]), 0.f);
        const float t3 = fmaxf(fmaf(dc, a[3], bg[3]), 0.f);
        const float t4 = fmaxf(fmaf(dc, a[4], bg[4]), 0.f);
        const float t5 = fmaxf(fmaf(dc, a[5], bg[5]), 0.f);
        const float t6 = fmaxf(fmaf(dc, a[6], bg[6]), 0.f);
        const float t7 = fmaxf(fmaf(dc, a[7], bg[7]), 0.f);
        uint4 o;
        o.x = ((uint)f2b(t1) << 16) | f2b(t0);
        o.y = ((uint)f2b(t3) << 16) | f2b(t2);
        o.z = ((uint)f2b(t5) << 16) | f2b(t4);
        o.w = ((uint)f2b(t7) << 16) | f2b(t6);
        *(uint4*)&ts[idx][coff] = o;
      }
    } else if (qt == 0) {
      *(uint4*)&ts[idx][coff] = make_uint4(0u, 0u, 0u, 0u);
    }
  }
  __syncthreads();

  // out = ts @ Wtc^T + bc : 2 row-blocks x 3 col-blocks = 6 MFMA tiles
  if (wid < 6) {
    const int rb = wid & 1, nb = wid >> 1;
    const int fr = lane & 15, fg = lane >> 4;
    f32x4 acc = (f32x4){0.f, 0.f, 0.f, 0.f};
#pragma unroll
    for (int ks = 0; ks < 4; ++ks) {
      const int kb = ks * 32 + fg * 8;
      bf16x8 aa = *(const bf16x8*)&ts[rb * 16 + fr][kb];
      bf16x8 bb = *(const bf16x8*)&Bs[nb * 16 + fr][kb];
      acc = __builtin_amdgcn_mfma_f32_16x16x32_bf16(aa, bb, acc, 0, 0, 0);
    }
    const int cn = nb * 16 + fr;
    if (cn < 40) {
      const float bv = bc[cn];
      const int r0 = row0 + rb * 16 + fg * 4;
#pragma unroll
      for (int i = 0; i < 4; ++i) {
        const int rr = r0 + i;
        if (rr < n) out[(size_t)rr * 40 + cn] = acc[i] + bv;
      }
    }
  }
}

extern "C" void kernel_launch(void* const* d_in, const int* in_sizes, int n_in,
                              void* d_out, int out_size, void* d_ws, size_t ws_size,
                              hipStream_t stream) {
  const float* x     = (const float*)d_in[0];
  const int*   ei    = (const int*)d_in[1];
  const float* W_in  = (const float*)d_in[2];
  const float* b_in  = (const float*)d_in[3];
  const float* W_gcn = (const float*)d_in[4];
  const float* b_gcn = (const float*)d_in[5];
  const float* W_cls = (const float*)d_in[6];
  const float* b_cls = (const float*)d_in[7];
  float* out = (float*)d_out;

  const int N = in_sizes[0] / 128;
  const int E = in_sizes[1] / 2;
  const int* row = ei;
  const int* col = ei + E;

  const int sortb = (E + CH_MAX - 1) / CH_MAX;   // 128 for E=600000
  const int chunk = (E + sortb - 1) / sortb;      // <= CH_MAX
  const int nbuck = (N + 127) >> 7;               // 391
  const int NT    = (N + 127) >> 7;               // 128-row GEMM tiles
  const int SPLIT = (NT + 1) >> 1;                // 196

  // d_ws layout (~31.5 MB)
  ushort* h      = (ushort*)d_ws;                 // N*128 bf16
  ushort* xws    = h + (size_t)N * 128;           // N*128 bf16
  ushort* Wti    = xws + (size_t)N * 128;         // 128x128
  ushort* Wtg    = Wti + 128 * 128;               // 128x128
  ushort* Wtc    = Wtg + 128 * 128;               // 48x128 zero-padded
  uint*   ebuf   = (uint*)(Wtc + 48 * 128);       // E
  int*    srcrow = (int*)(ebuf + E);              // E
  int*    H2     = srcrow + E;                    // NBUCK*sortb
  int*    Hs     = H2 + NBUCK * sortb;            // NBUCK+1
  int*    cursor = Hs + NBUCK + 1;                // NBUCK
  int*    P      = cursor + NBUCK;                // N
  float*  dinv   = (float*)(P + N);               // N

  // L1: weight prep || coarse chist
  k_L1_prep_chist<<<PREP_BLKS + sortb, 512, 0, stream>>>(
      W_in, W_gcn, W_cls, Wti, Wtg, Wtc, col, H2, E, chunk, sortb);

  // L2: bucket scan || G1a (h rows [0, SPLIT*128))
  k_L2_scan_g1a<<<1 + SPLIT, 512, 0, stream>>>(
      H2, Hs, cursor, sortb, x, Wti, b_in, h, N);

  // L3: reorder || G1b || G2a
  k_L3_reorder_g1b_g2a<<<sortb + (NT - SPLIT) + SPLIT, 512, 0, stream>>>(
      row, col, Hs, cursor, ebuf, E, chunk, sortb,
      x, Wti, b_in, Wtg, h, xws, N);

  // L4: fine sort -> srcrow/P/dinv || G2b
  k_L4_sort_g2b<<<nbuck + (NT - SPLIT), 512, 0, stream>>>(
      ebuf, Hs, srcrow, P, dinv, nbuck, h, Wtg, xws, N);

  // L5: out = relu(dinv[c]*(sum dinv[r]*xw[r] + dinv[c]*xw[c]) + b_gcn) @ W_cls + b_cls
  k_aggout<<<(N + 31) / 32, 512, 0, stream>>>(
      P, srcrow, xws, dinv, b_gcn, Wtc, b_cls, out, N);
}

// Round 15
// 77.323 us; speedup vs baseline: 1.4659x; 1.0300x over previous
//
#include <hip/hip_runtime.h>

// ---------------------------------------------------------------------------
// PYG_GCN: y = relu(x@W_in+b_in) -> GCNConv(W_gcn,b_gcn) -> relu -> @W_cls+b_cls
// N=50000, E=600000, D=128, C=40.
// R15: fused GEMM1+2 (h stays in LDS, R7-proven) split into THIRDS so every
// sort stage hides under GEMM work (incl. previously-naked sort2); aggout
// gather is quarter-per-node (4 node streams/wave, no cross-lane reduce).
//   L1 prep||chist -> L2 scan||G12a -> L3 reorder||G12b -> L4 sort2||G12c
//   -> L5 aggout
// ---------------------------------------------------------------------------

typedef __bf16 bf16x8 __attribute__((ext_vector_type(8)));
typedef float f32x4 __attribute__((ext_vector_type(4)));

#define NBUCK 512      // bucket = col>>7; used 0..390 for N=50000
#define CH_MAX 4704    // max edges per sort-chunk block
#define PREP_BLKS 76   // 38912 weight elements / 512
#define SCAP 1024      // aggout LDS edge window (32 nodes: mean 384)

__device__ __forceinline__ ushort f2b(float f) {  // fp32 -> bf16 RNE
  uint u = __float_as_uint(f);
  return (ushort)((u + 0x7FFFu + ((u >> 16) & 1u)) >> 16);
}
__device__ __forceinline__ float b2f_lo(uint u) { return __uint_as_float(u << 16); }
__device__ __forceinline__ float b2f_hi(uint u) { return __uint_as_float(u & 0xFFFF0000u); }

__device__ __forceinline__ void acc8s(float* a, uint4 v, float d) {
  a[0] = fmaf(d, b2f_lo(v.x), a[0]); a[1] = fmaf(d, b2f_hi(v.x), a[1]);
  a[2] = fmaf(d, b2f_lo(v.y), a[2]); a[3] = fmaf(d, b2f_hi(v.y), a[3]);
  a[4] = fmaf(d, b2f_lo(v.z), a[4]); a[5] = fmaf(d, b2f_hi(v.z), a[5]);
  a[6] = fmaf(d, b2f_lo(v.w), a[6]); a[7] = fmaf(d, b2f_hi(v.w), a[7]);
}

// ---------------- fused GEMM1+2 tile: 512 threads, 128 rows ----------------
// xws = (relu(x@Wti^T + b_in)) @ Wtg^T   (h lives only in LDS; unscaled out)
__device__ __forceinline__ void g12_tile_512(const float* __restrict__ x,
                                             const ushort* __restrict__ Wti,
                                             const ushort* __restrict__ Wtg,
                                             const float* __restrict__ b_in,
                                             ushort* __restrict__ xws,
                                             int nrows, int row0,
                                             char* smem, int tid) {
  ushort (*As)[136] = (ushort(*)[136])smem;                    // 128 rows
  ushort (*Bs)[136] = (ushort(*)[136])(smem + 128 * 136 * 2);  // 128 rows
#pragma unroll
  for (int q = 0; q < 4; ++q) {
    int f = tid + 512 * q;
    int r = f >> 4, cw = f & 15;
    *(uint4*)&Bs[r][cw * 8] = *(const uint4*)&Wti[r * 128 + cw * 8];
  }
#pragma unroll
  for (int q = 0; q < 8; ++q) {
    int f = tid + 512 * q;
    int r = f >> 5, kc = f & 31;
    float4 v = make_float4(0.f, 0.f, 0.f, 0.f);
    if (row0 + r < nrows) v = *(const float4*)&x[(size_t)(row0 + r) * 128 + kc * 4];
    ushort4 o;
    o.x = f2b(v.x); o.y = f2b(v.y); o.z = f2b(v.z); o.w = f2b(v.w);
    *(ushort4*)&As[r][kc * 4] = o;
  }
  __syncthreads();

  const int wid = tid >> 6, lane = tid & 63;
  const int fr = lane & 15, fg = lane >> 4;
  f32x4 acc[8];
#pragma unroll
  for (int nn = 0; nn < 8; ++nn) acc[nn] = (f32x4){0.f, 0.f, 0.f, 0.f};
#pragma unroll
  for (int ks = 0; ks < 4; ++ks) {
    const int kb = ks * 32 + fg * 8;
    bf16x8 a = *(const bf16x8*)&As[wid * 16 + fr][kb];
#pragma unroll
    for (int nn = 0; nn < 8; ++nn) {
      bf16x8 b = *(const bf16x8*)&Bs[nn * 16 + fr][kb];
      acc[nn] = __builtin_amdgcn_mfma_f32_16x16x32_bf16(a, b, acc[nn], 0, 0, 0);
    }
  }
  __syncthreads();  // all stage-1 reads done

  // h = relu(acc + b_in) -> bf16 back into As (D-frag layout); restage Wtg
#pragma unroll
  for (int nn = 0; nn < 8; ++nn) {
    const int cn = nn * 16 + fr;
    const float bv = b_in[cn];
#pragma unroll
    for (int i = 0; i < 4; ++i)
      As[wid * 16 + fg * 4 + i][cn] = f2b(fmaxf(acc[nn][i] + bv, 0.f));
  }
#pragma unroll
  for (int q = 0; q < 4; ++q) {
    int f = tid + 512 * q;
    int r = f >> 4, cw = f & 15;
    *(uint4*)&Bs[r][cw * 8] = *(const uint4*)&Wtg[r * 128 + cw * 8];
  }
  __syncthreads();

  f32x4 acc2[8];
#pragma unroll
  for (int nn = 0; nn < 8; ++nn) acc2[nn] = (f32x4){0.f, 0.f, 0.f, 0.f};
#pragma unroll
  for (int ks = 0; ks < 4; ++ks) {
    const int kb = ks * 32 + fg * 8;
    bf16x8 a = *(const bf16x8*)&As[wid * 16 + fr][kb];
#pragma unroll
    for (int nn = 0; nn < 8; ++nn) {
      bf16x8 b = *(const bf16x8*)&Bs[nn * 16 + fr][kb];
      acc2[nn] = __builtin_amdgcn_mfma_f32_16x16x32_bf16(a, b, acc2[nn], 0, 0, 0);
    }
  }
  const int r0 = row0 + wid * 16 + fg * 4;
#pragma unroll
  for (int nn = 0; nn < 8; ++nn) {
    const int cn = nn * 16 + fr;
#pragma unroll
    for (int i = 0; i < 4; ++i) {
      const int rr = r0 + i;
      if (rr < nrows) xws[(size_t)rr * 128 + cn] = f2b(acc2[nn][i]);
    }
  }
}

// ---------------- L1: weight prep [0,76) || coarse chist -------------------
__global__ __launch_bounds__(512) void k_L1_prep_chist(const float* __restrict__ Wi,
                                                       const float* __restrict__ Wg,
                                                       const float* __restrict__ Wc,
                                                       ushort* __restrict__ Ti,
                                                       ushort* __restrict__ Tg,
                                                       ushort* __restrict__ Tc,
                                                       const int* __restrict__ col,
                                                       int* __restrict__ H2,
                                                       int E, int chunk, int sortb) {
  __shared__ int hist[NBUCK];
  const int tid = threadIdx.x;
  if (blockIdx.x < PREP_BLKS) {
    int idx = blockIdx.x * 512 + tid;
    if (idx < 16384) {
      int c = idx >> 7, k = idx & 127;
      Ti[c * 128 + k] = f2b(Wi[k * 128 + c]);
    } else if (idx < 32768) {
      int j = idx - 16384;
      int c = j >> 7, k = j & 127;
      Tg[c * 128 + k] = f2b(Wg[k * 128 + c]);
    } else if (idx < 38912) {
      int j = idx - 32768;
      int c = j >> 7, k = j & 127;
      Tc[c * 128 + k] = (c < 40) ? f2b(Wc[k * 40 + c]) : (ushort)0;
    }
    return;
  }
  const int blk = blockIdx.x - PREP_BLKS;
  if (tid < NBUCK) hist[tid] = 0;
  __syncthreads();
  const int e0 = blk * chunk;
  const int cnt = min(chunk, E - e0);
  for (int i = tid; i < cnt; i += 512)
    atomicAdd(&hist[((unsigned)col[e0 + i]) >> 7], 1);
  __syncthreads();
  if (tid < NBUCK) H2[tid * sortb + blk] = hist[tid];
}

// ---------------- L2: block 0 = bucket scan; blocks 1.. = G12 tiles [0,T1) -
__global__ __launch_bounds__(512) void k_L2_scan_g12(const int* __restrict__ H2,
                                                     int* __restrict__ Hs,
                                                     int* __restrict__ cursor,
                                                     int sortb,
                                                     const float* __restrict__ x,
                                                     const ushort* __restrict__ Wti,
                                                     const ushort* __restrict__ Wtg,
                                                     const float* __restrict__ b_in,
                                                     ushort* __restrict__ xws,
                                                     int nrows) {
  __shared__ __align__(16) char smem[69632];
  const int tid = threadIdx.x;
  if (blockIdx.x == 0) {
    int* sd = (int*)smem;  // 512 ints
    int s = 0;
    const int4* p = (const int4*)&H2[tid * sortb];
    for (int j = 0; j < sortb / 4; ++j) { int4 v = p[j]; s += v.x + v.y + v.z + v.w; }
    sd[tid] = s;
    __syncthreads();
    for (int off = 1; off < 512; off <<= 1) {
      int u = (tid >= off) ? sd[tid - off] : 0;
      __syncthreads();
      sd[tid] += u;
      __syncthreads();
    }
    Hs[tid] = sd[tid] - s;          // exclusive
    if (tid == 511) Hs[NBUCK] = sd[511];
    cursor[tid] = 0;
    return;
  }
  g12_tile_512(x, Wti, Wtg, b_in, xws, nrows, (blockIdx.x - 1) * 128, smem, tid);
}

// ---------------- L3: reorder [0,sortb) || G12 tiles [T1,T2) ---------------
// ebuf record: (c_local<<16) | row  (row < 65536 since N=50000).
__global__ __launch_bounds__(512) void k_L3_reorder_g12(const int* __restrict__ row,
                                                        const int* __restrict__ col,
                                                        const int* __restrict__ Hs,
                                                        int* __restrict__ cursor,
                                                        uint* __restrict__ ebuf,
                                                        int E, int chunk, int sortb,
                                                        const float* __restrict__ x,
                                                        const ushort* __restrict__ Wti,
                                                        const ushort* __restrict__ Wtg,
                                                        const float* __restrict__ b_in,
                                                        ushort* __restrict__ xws,
                                                        int nrows, int tile0) {
  __shared__ __align__(16) char smem[69632];
  const int tid = threadIdx.x;
  if (blockIdx.x < (unsigned)sortb) {
    int* hist   = (int*)smem;              // NBUCK
    int* lstart = hist + NBUCK;            // NBUCK
    int* cnt2   = lstart + NBUCK;          // NBUCK
    int* obase  = cnt2 + NBUCK;            // NBUCK
    uint* data  = (uint*)(obase + NBUCK);  // CH_MAX
    int* gpos   = (int*)(data + CH_MAX);   // CH_MAX
    int* sd     = gpos + CH_MAX;           // 512
    hist[tid] = 0; cnt2[tid] = 0;
    __syncthreads();
    const int e0 = blockIdx.x * chunk;
    const int cnt = min(chunk, E - e0);
    for (int i = tid; i < cnt; i += 512)
      atomicAdd(&hist[((unsigned)col[e0 + i]) >> 7], 1);
    __syncthreads();
    const int h0 = hist[tid];
    sd[tid] = h0;
    __syncthreads();
    for (int off = 1; off < 512; off <<= 1) {
      int u = (tid >= off) ? sd[tid - off] : 0;
      __syncthreads();
      sd[tid] += u;
      __syncthreads();
    }
    lstart[tid] = sd[tid] - h0;
    obase[tid] = Hs[tid] + (h0 ? atomicAdd(&cursor[tid], h0) : 0);
    __syncthreads();
    for (int i = tid; i < cnt; i += 512) {
      const int c = col[e0 + i], r = row[e0 + i];
      const int b = ((unsigned)c) >> 7;
      const int rk = atomicAdd(&cnt2[b], 1);
      const int slot = lstart[b] + rk;
      data[slot] = ((uint)(c & 127) << 16) | (uint)r;
      gpos[slot] = obase[b] + rk;
    }
    __syncthreads();
    for (int i = tid; i < cnt; i += 512)
      ebuf[gpos[i]] = data[i];
    return;
  }
  g12_tile_512(x, Wti, Wtg, b_in, xws, nrows,
               (tile0 + (int)blockIdx.x - sortb) * 128, smem, tid);
}

// ---------------- L4: sort2 [0,nbuck) || G12 tiles [T2,NT) -----------------
// P[node] = END offset (seg = [P[c-1], P[c]), P[-1] := 0).
__global__ __launch_bounds__(512) void k_L4_sort_g12(const uint* __restrict__ ebuf,
                                                     const int* __restrict__ Hs,
                                                     int* __restrict__ srcrow,
                                                     int* __restrict__ P,
                                                     float* __restrict__ dinv,
                                                     int nbuck,
                                                     const float* __restrict__ x,
                                                     const ushort* __restrict__ Wti,
                                                     const ushort* __restrict__ Wtg,
                                                     const float* __restrict__ b_in,
                                                     ushort* __restrict__ xws,
                                                     int n, int tile0) {
  __shared__ __align__(16) char smem[69632];
  const int tid = threadIdx.x;
  if (blockIdx.x < (unsigned)nbuck) {
    int* cnt    = (int*)smem;        // 128
    int* lstart = cnt + 128;         // 128
    int* cnt2   = lstart + 128;      // 128
    int* sd     = cnt2 + 128;        // 512
    if (tid < 128) { cnt[tid] = 0; cnt2[tid] = 0; }
    __syncthreads();
    const int b = blockIdx.x;
    const int start = Hs[b];
    const int end = Hs[b + 1];
    for (int i = start + tid; i < end; i += 512)
      atomicAdd(&cnt[ebuf[i] >> 16], 1);
    __syncthreads();
    const int cv = (tid < 128) ? cnt[tid] : 0;
    sd[tid] = cv;
    __syncthreads();
    for (int off = 1; off < 128; off <<= 1) {
      int u = (tid >= off) ? sd[tid - off] : 0;
      __syncthreads();
      sd[tid] += u;
      __syncthreads();
    }
    if (tid < 128) {
      const int ex = sd[tid] - cv;
      lstart[tid] = ex;
      const int node = b * 128 + tid;
      if (node < n) {
        P[node] = start + ex + cv;
        dinv[node] = rsqrtf((float)cv + 1.0f);
      }
    }
    __syncthreads();
    for (int i = start + tid; i < end; i += 512) {
      const uint v = ebuf[i];
      const int c = v >> 16;
      const int rk = atomicAdd(&cnt2[c], 1);
      srcrow[start + lstart[c] + rk] = (int)(v & 0xFFFFu);
    }
    return;
  }
  g12_tile_512(x, Wti, Wtg, b_in, xws, n,
               (tile0 + (int)blockIdx.x - nbuck) * 128, smem, tid);
}

// ---------------- L5: fused aggregate + classifier -------------------------
// 512 threads / 32 nodes. Quarter-per-node gather: each 16-lane quarter owns
// one node (full 128-col row via lane-uint4); 4 node streams per wave, no
// cross-lane reduce. srcrow window + P boundaries staged in LDS.
__global__ __launch_bounds__(512) void k_aggout(const int* __restrict__ P,
                                                const int* __restrict__ srcrow,
                                                const ushort* __restrict__ xws,
                                                const float* __restrict__ dinv,
                                                const float* __restrict__ b_gcn,
                                                const ushort* __restrict__ Wtc,
                                                const float* __restrict__ bc,
                                                float* __restrict__ out, int n) {
  __shared__ ushort ts[32][136];
  __shared__ ushort Bs[48][136];
  __shared__ int eLds[SCAP];
  __shared__ int pb[33];
  __shared__ int nextn;
  const int tid = threadIdx.x;
  const int row0 = blockIdx.x * 32;
#pragma unroll
  for (int q = 0; q < 2; ++q) {
    int f = tid + 512 * q;
    if (f < 768) {
      int r = f >> 4, cw = f & 15;
      *(uint4*)&Bs[r][cw * 8] = *(const uint4*)&Wtc[r * 128 + cw * 8];
    }
  }
  if (tid < 33) {
    int node = row0 + tid - 1;
    pb[tid] = (node < 0) ? 0 : P[node < n ? node : (n - 1)];
  }
  if (tid == 0) nextn = 0;
  __syncthreads();
  const int sStart = pb[0];
  const int tot = pb[32] - sStart;
  const bool inL = (tot <= SCAP);
  if (inL) {
    for (int i = tid; i < tot; i += 512) eLds[i] = srcrow[sStart + i];
  }
  __syncthreads();

  const int wid = tid >> 6, lane = tid & 63;
  const int lq = lane & 15;                   // lane in quarter
  const size_t coff = (size_t)lq * 8;         // 8 cols per lane

  float bg[8];
#pragma unroll
  for (int j = 0; j < 8; ++j) bg[j] = b_gcn[lq * 8 + j];

  // quarter-per-node dynamic queue
  for (;;) {
    int idx;
    if (lq == 0) idx = atomicAdd(&nextn, 1);
    idx = __shfl(idx, lane & 48);   // broadcast within quarter
    if (idx >= 32) break;
    const int c = row0 + idx;
    if (c < n) {
      const int len = pb[idx + 1] - pb[idx];
      float a[8];
#pragma unroll
      for (int j = 0; j < 8; ++j) a[j] = 0.f;
      if (inL) {
        const int base = pb[idx] - sStart;
        int e = 0;
        for (; e + 2 <= len; e += 2) {
          const int r0 = eLds[base + e], r1 = eLds[base + e + 1];
          const float d0 = dinv[r0], d1 = dinv[r1];
          const uint4 v0 = *(const uint4*)&xws[(size_t)r0 * 128 + coff];
          const uint4 v1 = *(const uint4*)&xws[(size_t)r1 * 128 + coff];
          acc8s(a, v0, d0);
          acc8s(a, v1, d1);
        }
        if (e < len) {
          const int r = eLds[base + e];
          const float d = dinv[r];
          const uint4 v = *(const uint4*)&xws[(size_t)r * 128 + coff];
          acc8s(a, v, d);
        }
      } else {
        const int base = pb[idx];
        int e = 0;
        for (; e + 2 <= len; e += 2) {
          const int r0 = srcrow[base + e], r1 = srcrow[base + e + 1];
          const float d0 = dinv[r0], d1 = dinv[r1];
          const uint4 v0 = *(const uint4*)&xws[(size_t)r0 * 128 + coff];
          const uint4 v1 = *(const uint4*)&xws[(size_t)r1 * 128 + coff];
          acc8s(a, v0, d0);
          acc8s(a, v1, d1);
        }
        if (e < len) {
          const int r = srcrow[base + e];
          const float d = dinv[r];
          const uint4 v = *(const uint4*)&xws[(size_t)r * 128 + coff];
          acc8s(a, v, d);
        }
      }
      const uint4 sv = *(const uint4*)&xws[(size_t)c * 128 + coff];  // self
      const float dc = dinv[c];
      acc8s(a, sv, dc);
      const float t0 = fmaxf(fmaf(dc, a[0], bg[0]), 0.f);
      const float t1 = fmaxf(fmaf(dc, a[1], bg[1]), 0.f);
      const float t2 = fmaxf(fmaf(dc, a[2], bg[2]), 0.f);
      const float t3 = fmaxf(fmaf(dc, a[3], bg[3]), 0.f);
      const float t4 = fmaxf(fmaf(dc, a[4], bg[4]), 0.f);
      const float t5 = fmaxf(fmaf(dc, a[5], bg[5]), 0.f);
      const float t6 = fmaxf(fmaf(dc, a[6], bg[6]), 0.f);
      const float t7 = fmaxf(fmaf(dc, a[7], bg[7]), 0.f);
      uint4 o;
      o.x = ((uint)f2b(t1) << 16) | f2b(t0);
      o.y = ((uint)f2b(t3) << 16) | f2b(t2);
      o.z = ((uint)f2b(t5) << 16) | f2b(t4);
      o.w = ((uint)f2b(t7) << 16) | f2b(t6);
      *(uint4*)&ts[idx][coff] = o;
    } else {
      *(uint4*)&ts[idx][coff] = make_uint4(0u, 0u, 0u, 0u);
    }
  }
  __syncthreads();

  // out = ts @ Wtc^T + bc : 2 row-blocks x 3 col-blocks = 6 MFMA tiles
  if (wid < 6) {
    const int rb = wid & 1, nb = wid >> 1;
    const int fr = lane & 15, fg = lane >> 4;
    f32x4 acc = (f32x4){0.f, 0.f, 0.f, 0.f};
#pragma unroll
    for (int ks = 0; ks < 4; ++ks) {
      const int kb = ks * 32 + fg * 8;
      bf16x8 aa = *(const bf16x8*)&ts[rb * 16 + fr][kb];
      bf16x8 bb = *(const bf16x8*)&Bs[nb * 16 + fr][kb];
      acc = __builtin_amdgcn_mfma_f32_16x16x32_bf16(aa, bb, acc, 0, 0, 0);
    }
    const int cn = nb * 16 + fr;
    if (cn < 40) {
      const float bv = bc[cn];
      const int r0 = row0 + rb * 16 + fg * 4;
#pragma unroll
      for (int i = 0; i < 4; ++i) {
        const int rr = r0 + i;
        if (rr < n) out[(size_t)rr * 40 + cn] = acc[i] + bv;
      }
    }
  }
}

extern "C" void kernel_launch(void* const* d_in, const int* in_sizes, int n_in,
                              void* d_out, int out_size, void* d_ws, size_t ws_size,
                              hipStream_t stream) {
  const float* x     = (const float*)d_in[0];
  const int*   ei    = (const int*)d_in[1];
  const float* W_in  = (const float*)d_in[2];
  const float* b_in  = (const float*)d_in[3];
  const float* W_gcn = (const float*)d_in[4];
  const float* b_gcn = (const float*)d_in[5];
  const float* W_cls = (const float*)d_in[6];
  const float* b_cls = (const float*)d_in[7];
  float* out = (float*)d_out;

  const int N = in_sizes[0] / 128;
  const int E = in_sizes[1] / 2;
  const int* row = ei;
  const int* col = ei + E;

  const int sortb = (E + CH_MAX - 1) / CH_MAX;   // 128 for E=600000
  const int chunk = (E + sortb - 1) / sortb;      // <= CH_MAX
  const int nbuck = (N + 127) >> 7;               // 391
  const int NT    = (N + 127) >> 7;               // 128-row G12 tiles (391)
  const int T1    = NT / 3;                       // 130
  const int T2    = (2 * NT) / 3;                 // 260

  // d_ws layout (~18.6 MB)
  ushort* xws    = (ushort*)d_ws;                 // N*128 bf16
  ushort* Wti    = xws + (size_t)N * 128;         // 128x128
  ushort* Wtg    = Wti + 128 * 128;               // 128x128
  ushort* Wtc    = Wtg + 128 * 128;               // 48x128 zero-padded
  uint*   ebuf   = (uint*)(Wtc + 48 * 128);       // E
  int*    srcrow = (int*)(ebuf + E);              // E
  int*    H2     = srcrow + E;                    // NBUCK*sortb
  int*    Hs     = H2 + NBUCK * sortb;            // NBUCK+1
  int*    cursor = Hs + NBUCK + 1;                // NBUCK
  int*    P      = cursor + NBUCK;                // N
  float*  dinv   = (float*)(P + N);               // N

  // L1: weight prep || coarse chist
  k_L1_prep_chist<<<PREP_BLKS + sortb, 512, 0, stream>>>(
      W_in, W_gcn, W_cls, Wti, Wtg, Wtc, col, H2, E, chunk, sortb);

  // L2: bucket scan || G12 tiles [0, T1)
  k_L2_scan_g12<<<1 + T1, 512, 0, stream>>>(
      H2, Hs, cursor, sortb, x, Wti, Wtg, b_in, xws, N);

  // L3: reorder || G12 tiles [T1, T2)
  k_L3_reorder_g12<<<sortb + (T2 - T1), 512, 0, stream>>>(
      row, col, Hs, cursor, ebuf, E, chunk, sortb,
      x, Wti, Wtg, b_in, xws, N, T1);

  // L4: fine sort -> srcrow/P/dinv || G12 tiles [T2, NT)
  k_L4_sort_g12<<<nbuck + (NT - T2), 512, 0, stream>>>(
      ebuf, Hs, srcrow, P, dinv, nbuck, x, Wti, Wtg, b_in, xws, N, T2);

  // L5: out = relu(dinv[c]*(sum dinv[r]*xw[r] + dinv[c]*xw[c]) + b_gcn) @ W_cls + b_cls
  k_aggout<<<(N + 31) / 32, 512, 0, stream>>>(
      P, srcrow, xws, dinv, b_gcn, Wtc, b_cls, out, N);
}